// Round 2
// baseline (920.760 us; speedup 1.0000x reference)
//
#include <hip/hip_runtime.h>
#include <math.h>

#define V_N 8192
#define D_F 128
#define E_N 262144
#define K_N 512
#define DMAXF 0.5f
#define EPSW 1e-8f
#define EPSL 1e-5f

// ---------- transpose pmat (K x V) -> PT (V x K) ----------
__global__ __launch_bounds__(256) void k_transpose(const float* __restrict__ P, float* __restrict__ PT) {
  __shared__ float tile[32][33];
  int v0 = blockIdx.x * 32, k0 = blockIdx.y * 32;
  int tx = threadIdx.x, ty = threadIdx.y;
#pragma unroll
  for (int i = 0; i < 4; ++i)
    tile[ty + i * 8][tx] = P[(size_t)(k0 + ty + i * 8) * V_N + v0 + tx];
  __syncthreads();
#pragma unroll
  for (int i = 0; i < 4; ++i)
    PT[(size_t)(v0 + ty + i * 8) * K_N + k0 + tx] = tile[tx][ty + i * 8];
}

// ---------- per-edge weight, degree accumulation, strong-edge compaction ----------
__global__ __launch_bounds__(256) void k_edge(const float* __restrict__ X, const int* __restrict__ ei,
                                              float* __restrict__ deg, int* __restrict__ cnt,
                                              int* __restrict__ si, int* __restrict__ sj,
                                              float* __restrict__ sw) {
  int t = blockIdx.x * 256 + threadIdx.x;
  int e = t >> 4, lane = t & 15;           // 16 lanes per edge
  int i = ei[e], j = ei[E_N + e];
  const float4* xi = (const float4*)(X + (size_t)i * D_F);
  const float4* xj = (const float4*)(X + (size_t)j * D_F);
  float4 a0 = xi[lane * 2], a1 = xi[lane * 2 + 1];
  float4 b0 = xj[lane * 2], b1 = xj[lane * 2 + 1];
  float d = 0.f, dx;
  dx = a0.x - b0.x; d += dx * dx;
  dx = a0.y - b0.y; d += dx * dx;
  dx = a0.z - b0.z; d += dx * dx;
  dx = a0.w - b0.w; d += dx * dx;
  dx = a1.x - b1.x; d += dx * dx;
  dx = a1.y - b1.y; d += dx * dx;
  dx = a1.z - b1.z; d += dx * dx;
  dx = a1.w - b1.w; d += dx * dx;
  d += __shfl_xor(d, 1);
  d += __shfl_xor(d, 2);
  d += __shfl_xor(d, 4);
  d += __shfl_xor(d, 8);
  if (lane == 0) {
    bool strong = (d <= DMAXF);
    float w = strong ? expf(-d) : EPSW;
    atomicAdd(&deg[i], w);
    atomicAdd(&deg[j], w);
    if (strong) {
      int p = atomicAdd(cnt, 1);
      si[p] = i; sj[p] = j; sw[p] = w;
    }
  }
}

// ---------- scatter strong edges: Y[i] -= w*PT[j], Y[j] -= w*PT[i] ----------
__global__ __launch_bounds__(128) void k_scatter(const int* __restrict__ cnt, const int* __restrict__ si,
                                                 const int* __restrict__ sj, const float* __restrict__ sw,
                                                 const float* __restrict__ PT, float* __restrict__ Y) {
  int m = *cnt;
  int k0 = threadIdx.x * 4;                 // 128 threads cover 512 cols
  for (int e = blockIdx.x; e < m; e += gridDim.x) {
    int i = si[e], j = sj[e];
    float w = sw[e];
    float4 pj = *(const float4*)&PT[(size_t)j * K_N + k0];
    float4 pi = *(const float4*)&PT[(size_t)i * K_N + k0];
    float* yi = &Y[(size_t)i * K_N + k0];
    float* yj = &Y[(size_t)j * K_N + k0];
    atomicAdd(yi + 0, -w * pj.x); atomicAdd(yi + 1, -w * pj.y);
    atomicAdd(yi + 2, -w * pj.z); atomicAdd(yi + 3, -w * pj.w);
    atomicAdd(yj + 0, -w * pi.x); atomicAdd(yj + 1, -w * pi.y);
    atomicAdd(yj + 2, -w * pi.z); atomicAdd(yj + 3, -w * pi.w);
  }
}

// ---------- init L_adj = eps * I ----------
__global__ __launch_bounds__(256) void k_init(float* __restrict__ La) {
  int idx = blockIdx.x * 256 + threadIdx.x;
  La[idx] = ((idx >> 9) == (idx & 511)) ? EPSL : 0.f;
}

// ---------- L_adj += P @ (deg .* PT + Y), split-K over V ----------
#define GT_K 16
__global__ __launch_bounds__(256) void k_gemm(const float* __restrict__ P, const float* __restrict__ PT,
                                              const float* __restrict__ Y, const float* __restrict__ deg,
                                              float* __restrict__ La) {
  __shared__ float As[GT_K][68];   // As[k][r]
  __shared__ float Bs[GT_K][68];   // Bs[k][c]
  int a0 = blockIdx.x * 64, b0 = blockIdx.y * 64;
  int v0 = blockIdx.z * 1024;
  int tid = threadIdx.x;
  int rt = tid >> 4, ct = tid & 15;
  int r0 = rt * 4, c0 = ct * 4;
  float acc[4][4];
#pragma unroll
  for (int i = 0; i < 4; ++i)
#pragma unroll
    for (int j = 0; j < 4; ++j) acc[i][j] = 0.f;

  for (int kc = 0; kc < 1024; kc += GT_K) {
    { // load A tile (64 rows x 16 k), store transposed
      int r = tid >> 2, kq = (tid & 3) * 4;
      float4 f = *(const float4*)&P[(size_t)(a0 + r) * V_N + v0 + kc + kq];
      As[kq + 0][r] = f.x; As[kq + 1][r] = f.y; As[kq + 2][r] = f.z; As[kq + 3][r] = f.w;
    }
    { // load B tile (16 k x 64 cols), B = deg*PT + Y
      int k = tid >> 4, cq = (tid & 15) * 4;
      int v = v0 + kc + k;
      float4 fy = *(const float4*)&Y[(size_t)v * K_N + b0 + cq];
      float4 fp = *(const float4*)&PT[(size_t)v * K_N + b0 + cq];
      float dv = deg[v];
      float4 b;
      b.x = fy.x + dv * fp.x; b.y = fy.y + dv * fp.y;
      b.z = fy.z + dv * fp.z; b.w = fy.w + dv * fp.w;
      *(float4*)&Bs[k][cq] = b;
    }
    __syncthreads();
#pragma unroll
    for (int k = 0; k < GT_K; ++k) {
      float4 av = *(const float4*)&As[k][r0];
      float4 bv = *(const float4*)&Bs[k][c0];
      acc[0][0] += av.x * bv.x; acc[0][1] += av.x * bv.y; acc[0][2] += av.x * bv.z; acc[0][3] += av.x * bv.w;
      acc[1][0] += av.y * bv.x; acc[1][1] += av.y * bv.y; acc[1][2] += av.y * bv.z; acc[1][3] += av.y * bv.w;
      acc[2][0] += av.z * bv.x; acc[2][1] += av.z * bv.y; acc[2][2] += av.z * bv.z; acc[2][3] += av.z * bv.w;
      acc[3][0] += av.w * bv.x; acc[3][1] += av.w * bv.y; acc[3][2] += av.w * bv.z; acc[3][3] += av.w * bv.w;
    }
    __syncthreads();
  }
#pragma unroll
  for (int i = 0; i < 4; ++i)
#pragma unroll
    for (int j = 0; j < 4; ++j)
      atomicAdd(&La[(size_t)(a0 + r0 + i) * K_N + b0 + c0 + j], acc[i][j]);
}

// ---------- trace = sum(L_adj * targets^T) ----------
__global__ __launch_bounds__(256) void k_trace(const float* __restrict__ La, const float* __restrict__ T,
                                               float* __restrict__ tr) {
  int idx = blockIdx.x * 256 + threadIdx.x;
  float v = La[idx] * T[(size_t)(idx & 511) * K_N + (idx >> 9)];
  v += __shfl_down(v, 32); v += __shfl_down(v, 16); v += __shfl_down(v, 8);
  v += __shfl_down(v, 4);  v += __shfl_down(v, 2);  v += __shfl_down(v, 1);
  if ((threadIdx.x & 63) == 0) atomicAdd(tr, v);
}

// ---------- single-workgroup blocked Cholesky logdet (block 0: La in-place; block 1: targets -> Lw1) ----------
__global__ __launch_bounds__(1024) void k_chol(float* La, const float* T, float* Lw1, float* ld) {
  float* dst = (blockIdx.x == 0) ? La : Lw1;
  const float* src = (blockIdx.x == 0) ? (const float*)La : T;
  __shared__ float panel[K_N][33];   // 67.5 KB
  __shared__ float histT[32][36];    // 4.6 KB
  int tid = threadIdx.x;
  float logacc = 0.f;
  int rt = tid >> 3, ct = tid & 7;
  int r0 = rt << 2, c0 = ct << 2;

  for (int pb = 0; pb < K_N / 32; ++pb) {
    int j0 = pb * 32;
    int rows = K_N - j0;
    // load panel (rows x 32) from src
    for (int idx = tid; idx < rows * 32; idx += 1024) {
      int r = idx >> 5, c = idx & 31;
      panel[r][c] = src[(size_t)(j0 + r) * K_N + j0 + c];
    }
    __syncthreads();

    // history update: panel -= L[j0+r, :j0] @ L[j0+c, :j0]^T  (4x4 register tiles)
    int nslots = (rows >> 2) << 3;
    float acc[4][4];
#pragma unroll
    for (int i = 0; i < 4; ++i)
#pragma unroll
      for (int jj = 0; jj < 4; ++jj) acc[i][jj] = 0.f;

    for (int kb = 0; kb < pb; ++kb) {
      { int c = tid >> 5, k = tid & 31;
        histT[k][c] = dst[(size_t)(j0 + c) * K_N + kb * 32 + k]; }
      __syncthreads();
      if (tid < nslots) {
        const float* arow = &dst[(size_t)(j0 + r0) * K_N + kb * 32];
#pragma unroll
        for (int kk = 0; kk < 32; kk += 4) {
          float av[4][4];
#pragma unroll
          for (int i = 0; i < 4; ++i) {
            float4 f = *(const float4*)(arow + (size_t)i * K_N + kk);
            av[i][0] = f.x; av[i][1] = f.y; av[i][2] = f.z; av[i][3] = f.w;
          }
#pragma unroll
          for (int t = 0; t < 4; ++t) {
            float4 b = *(const float4*)&histT[kk + t][c0];
#pragma unroll
            for (int i = 0; i < 4; ++i) {
              acc[i][0] += av[i][t] * b.x;
              acc[i][1] += av[i][t] * b.y;
              acc[i][2] += av[i][t] * b.z;
              acc[i][3] += av[i][t] * b.w;
            }
          }
        }
      }
      __syncthreads();
    }
    if (pb > 0 && tid < nslots) {
#pragma unroll
      for (int i = 0; i < 4; ++i)
#pragma unroll
        for (int jj = 0; jj < 4; ++jj)
          panel[r0 + i][c0 + jj] -= acc[i][jj];
    }
    __syncthreads();

    // factor 32x32 diag block in-register by wave 0 (barrier-free, shfl-based)
    if (tid < 64) {
      int r = tid & 31;
      float a[32];
#pragma unroll
      for (int c = 0; c < 32; ++c) a[c] = panel[r][c];
      float ls = 0.f;
#pragma unroll
      for (int c = 0; c < 32; ++c) {
        float dc = __shfl(a[c], c);      // fully-updated diagonal (= L_cc^2)
        ls += logf(dc);
        float s = sqrtf(dc);
        a[c] = a[c] / s;                 // scale column c
#pragma unroll
        for (int k = c + 1; k < 32; ++k)
          a[k] -= a[c] * __shfl(a[c], k);
      }
      if (tid < 32) {
#pragma unroll
        for (int c = 0; c < 32; ++c) panel[r][c] = a[c];
      }
      if (tid == 0) logacc += ls;
    }
    __syncthreads();

    // TRSM: rows 32..rows-1, row-parallel forward substitution (barrier-free)
    {
      int r = 32 + tid;
      if (r < rows) {
        float x[32];
#pragma unroll
        for (int c = 0; c < 32; ++c) x[c] = panel[r][c];
#pragma unroll
        for (int c = 0; c < 32; ++c) {
          x[c] = x[c] / panel[c][c];
#pragma unroll
          for (int k = c + 1; k < 32; ++k)
            x[k] -= x[c] * panel[k][c];
        }
#pragma unroll
        for (int c = 0; c < 32; ++c) panel[r][c] = x[c];
      }
    }
    __syncthreads();

    // write panel back
    for (int idx = tid; idx < rows * 32; idx += 1024) {
      int r = idx >> 5, c = idx & 31;
      dst[(size_t)(j0 + r) * K_N + j0 + c] = panel[r][c];
    }
    __syncthreads();
  }
  if (tid == 0) ld[blockIdx.x] = logacc;
}

// ---------- combine ----------
__global__ void k_combine(const float* __restrict__ ld, const float* __restrict__ tr, float* __restrict__ out) {
  out[0] = -ld[0] - ld[1] - (float)K_N + tr[0];
}

extern "C" void kernel_launch(void* const* d_in, const int* in_sizes, int n_in,
                              void* d_out, int out_size, void* d_ws, size_t ws_size,
                              hipStream_t stream) {
  const float* X  = (const float*)d_in[0];   // inputs  [V,128]
  const float* T  = (const float*)d_in[1];   // targets [K,K]
  const int*   ei = (const int*)d_in[2];     // edge_index [2,E]
  const float* P  = (const float*)d_in[3];   // pmat [K,V]
  float* out = (float*)d_out;
  char* ws = (char*)d_ws;

  // workspace layout (bytes)
  int*   cnt = (int*)(ws + 0);
  float* tr  = (float*)(ws + 16);
  float* ld  = (float*)(ws + 32);
  float* deg = (float*)(ws + 256);                  // V floats
  float* PT  = (float*)(ws + 33024);                // V*K floats (16 MB)
  float* Y   = (float*)(ws + 16810240);             // V*K floats (16 MB)
  int*   si  = (int*)(ws + 33587456);               // E ints
  int*   sj  = (int*)(ws + 34636032);               // E ints
  float* sw  = (float*)(ws + 35684608);             // E floats
  float* La  = (float*)(ws + 36733184);             // K*K floats
  float* Lw1 = Y;                                   // reuse Y region (dead after GEMM) for targets' L

  hipMemsetAsync(ws, 0, 33024, stream);                       // cnt, tr, ld, deg
  hipMemsetAsync(Y, 0, (size_t)V_N * K_N * sizeof(float), stream);

  k_transpose<<<dim3(V_N / 32, K_N / 32), dim3(32, 8), 0, stream>>>(P, PT);
  k_edge<<<E_N / 16, 256, 0, stream>>>(X, ei, deg, cnt, si, sj, sw);
  k_scatter<<<2048, 128, 0, stream>>>(cnt, si, sj, sw, PT, Y);
  k_init<<<K_N * K_N / 256, 256, 0, stream>>>(La);
  k_gemm<<<dim3(8, 8, 8), 256, 0, stream>>>(P, PT, Y, deg, La);
  k_trace<<<K_N * K_N / 256, 256, 0, stream>>>(La, T, tr);
  k_chol<<<2, 1024, 0, stream>>>(La, T, Lw1, ld);
  k_combine<<<1, 1, 0, stream>>>(ld, tr, out);
}

// Round 3
// 745.280 us; speedup vs baseline: 1.2355x; 1.2355x over previous
//
#include <hip/hip_runtime.h>
#include <math.h>

#define V_N 8192
#define D_F 128
#define E_N 262144
#define K_N 512
#define DMAXF 0.5f
#define EPSW 1e-8f
#define EPSL 1e-5f
#define MAX_SE 32768

// ---------- transpose pmat (K x V) -> PT (V x K) ----------
__global__ __launch_bounds__(256) void k_transpose(const float* __restrict__ P, float* __restrict__ PT) {
  __shared__ float tile[32][33];
  int v0 = blockIdx.x * 32, k0 = blockIdx.y * 32;
  int tx = threadIdx.x, ty = threadIdx.y;
#pragma unroll
  for (int i = 0; i < 4; ++i)
    tile[ty + i * 8][tx] = P[(size_t)(k0 + ty + i * 8) * V_N + v0 + tx];
  __syncthreads();
#pragma unroll
  for (int i = 0; i < 4; ++i)
    PT[(size_t)(v0 + ty + i * 8) * K_N + k0 + tx] = tile[tx][ty + i * 8];
}

// ---------- per-edge weight, degree accumulation, strong-edge dedup+compaction ----------
__global__ __launch_bounds__(256) void k_edge(const float* __restrict__ X, const int* __restrict__ ei,
                                              float* __restrict__ deg, int* __restrict__ cnt,
                                              int* __restrict__ si, int* __restrict__ sj,
                                              float* __restrict__ sw, unsigned* __restrict__ htab) {
  int t = blockIdx.x * 256 + threadIdx.x;
  int e = t >> 4, lane = t & 15;           // 16 lanes per edge
  int i = ei[e], j = ei[E_N + e];
  const float4* xi = (const float4*)(X + (size_t)i * D_F);
  const float4* xj = (const float4*)(X + (size_t)j * D_F);
  float4 a0 = xi[lane * 2], a1 = xi[lane * 2 + 1];
  float4 b0 = xj[lane * 2], b1 = xj[lane * 2 + 1];
  float d = 0.f, dx;
  dx = a0.x - b0.x; d += dx * dx;
  dx = a0.y - b0.y; d += dx * dx;
  dx = a0.z - b0.z; d += dx * dx;
  dx = a0.w - b0.w; d += dx * dx;
  dx = a1.x - b1.x; d += dx * dx;
  dx = a1.y - b1.y; d += dx * dx;
  dx = a1.z - b1.z; d += dx * dx;
  dx = a1.w - b1.w; d += dx * dx;
  d += __shfl_xor(d, 1);
  d += __shfl_xor(d, 2);
  d += __shfl_xor(d, 4);
  d += __shfl_xor(d, 8);
  if (lane == 0) {
    if (d > DMAXF) {
      // weak edge: off-diag contribution negligible; dup-count error ~1e-8
      atomicAdd(&deg[i], EPSW);
      atomicAdd(&deg[j], EPSW);
    } else {
      float w = expf(-d);
      unsigned a = (unsigned)min(i, j), b = (unsigned)max(i, j);
      unsigned key = a * 8192u + b;
      unsigned h = (key * 2654435761u) >> 16;
      bool isnew = false;
      for (int probe = 0; probe < 65536; ++probe) {
        unsigned slot = (h + (unsigned)probe) & 65535u;
        unsigned prev = atomicCAS(&htab[slot], 0xFFFFFFFFu, key);
        if (prev == 0xFFFFFFFFu) { isnew = true; break; }
        if (prev == key) break;   // duplicate pair -> reference counts it once
      }
      if (isnew) {
        atomicAdd(&deg[i], w);
        atomicAdd(&deg[j], w);
        int p = atomicAdd(cnt, 1);
        if (p < MAX_SE) { si[p] = i; sj[p] = j; sw[p] = w; }
      }
    }
  }
}

// ---------- scatter strong edges: Y[i] -= w*PT[j], Y[j] -= w*PT[i] ----------
__global__ __launch_bounds__(128) void k_scatter(const int* __restrict__ cnt, const int* __restrict__ si,
                                                 const int* __restrict__ sj, const float* __restrict__ sw,
                                                 const float* __restrict__ PT, float* __restrict__ Y) {
  int m = min(*cnt, MAX_SE);
  int k0 = threadIdx.x * 4;                 // 128 threads cover 512 cols
  for (int e = blockIdx.x; e < m; e += gridDim.x) {
    int i = si[e], j = sj[e];
    float w = sw[e];
    float4 pj = *(const float4*)&PT[(size_t)j * K_N + k0];
    float4 pi = *(const float4*)&PT[(size_t)i * K_N + k0];
    float* yi = &Y[(size_t)i * K_N + k0];
    float* yj = &Y[(size_t)j * K_N + k0];
    atomicAdd(yi + 0, -w * pj.x); atomicAdd(yi + 1, -w * pj.y);
    atomicAdd(yi + 2, -w * pj.z); atomicAdd(yi + 3, -w * pj.w);
    atomicAdd(yj + 0, -w * pi.x); atomicAdd(yj + 1, -w * pi.y);
    atomicAdd(yj + 2, -w * pi.z); atomicAdd(yj + 3, -w * pi.w);
  }
}

// ---------- init L_adj = eps * I ----------
__global__ __launch_bounds__(256) void k_init(float* __restrict__ La) {
  int idx = blockIdx.x * 256 + threadIdx.x;
  La[idx] = ((idx >> 9) == (idx & 511)) ? EPSL : 0.f;
}

// ---------- L_adj += P @ (deg .* PT + Y), split-K over V ----------
#define GT_K 16
__global__ __launch_bounds__(256) void k_gemm(const float* __restrict__ P, const float* __restrict__ PT,
                                              const float* __restrict__ Y, const float* __restrict__ deg,
                                              float* __restrict__ La) {
  __shared__ float As[GT_K][68];   // As[k][r]
  __shared__ float Bs[GT_K][68];   // Bs[k][c]
  int a0 = blockIdx.x * 64, b0 = blockIdx.y * 64;
  int v0 = blockIdx.z * 1024;
  int tid = threadIdx.x;
  int rt = tid >> 4, ct = tid & 15;
  int r0 = rt * 4, c0 = ct * 4;
  float acc[4][4];
#pragma unroll
  for (int i = 0; i < 4; ++i)
#pragma unroll
    for (int j = 0; j < 4; ++j) acc[i][j] = 0.f;

  for (int kc = 0; kc < 1024; kc += GT_K) {
    { // load A tile (64 rows x 16 k), store transposed
      int r = tid >> 2, kq = (tid & 3) * 4;
      float4 f = *(const float4*)&P[(size_t)(a0 + r) * V_N + v0 + kc + kq];
      As[kq + 0][r] = f.x; As[kq + 1][r] = f.y; As[kq + 2][r] = f.z; As[kq + 3][r] = f.w;
    }
    { // load B tile (16 k x 64 cols), B = deg*PT + Y
      int k = tid >> 4, cq = (tid & 15) * 4;
      int v = v0 + kc + k;
      float4 fy = *(const float4*)&Y[(size_t)v * K_N + b0 + cq];
      float4 fp = *(const float4*)&PT[(size_t)v * K_N + b0 + cq];
      float dv = deg[v];
      float4 b;
      b.x = fy.x + dv * fp.x; b.y = fy.y + dv * fp.y;
      b.z = fy.z + dv * fp.z; b.w = fy.w + dv * fp.w;
      *(float4*)&Bs[k][cq] = b;
    }
    __syncthreads();
#pragma unroll
    for (int k = 0; k < GT_K; ++k) {
      float4 av = *(const float4*)&As[k][r0];
      float4 bv = *(const float4*)&Bs[k][c0];
      acc[0][0] += av.x * bv.x; acc[0][1] += av.x * bv.y; acc[0][2] += av.x * bv.z; acc[0][3] += av.x * bv.w;
      acc[1][0] += av.y * bv.x; acc[1][1] += av.y * bv.y; acc[1][2] += av.y * bv.z; acc[1][3] += av.y * bv.w;
      acc[2][0] += av.z * bv.x; acc[2][1] += av.z * bv.y; acc[2][2] += av.z * bv.z; acc[2][3] += av.z * bv.w;
      acc[3][0] += av.w * bv.x; acc[3][1] += av.w * bv.y; acc[3][2] += av.w * bv.z; acc[3][3] += av.w * bv.w;
    }
    __syncthreads();
  }
#pragma unroll
  for (int i = 0; i < 4; ++i)
#pragma unroll
    for (int j = 0; j < 4; ++j)
      atomicAdd(&La[(size_t)(a0 + r0 + i) * K_N + b0 + c0 + j], acc[i][j]);
}

// ---------- trace = sum(L_adj * targets^T) ----------
__global__ __launch_bounds__(256) void k_trace(const float* __restrict__ La, const float* __restrict__ T,
                                               float* __restrict__ tr) {
  int idx = blockIdx.x * 256 + threadIdx.x;
  float v = La[idx] * T[(size_t)(idx & 511) * K_N + (idx >> 9)];
  v += __shfl_down(v, 32); v += __shfl_down(v, 16); v += __shfl_down(v, 8);
  v += __shfl_down(v, 4);  v += __shfl_down(v, 2);  v += __shfl_down(v, 1);
  if ((threadIdx.x & 63) == 0) atomicAdd(tr, v);
}

// ---------- in-register 32x32 Cholesky factor of sm[o:o+32][o:o+32] by wave 0 ----------
__device__ __forceinline__ void factor32(float (*sm)[65], int o, int tid, float& logacc) {
  if (tid < 64) {
    int r = tid & 31;
    float a[32];
#pragma unroll
    for (int c = 0; c < 32; ++c) a[c] = sm[o + r][o + c];
    float ls = 0.f;
#pragma unroll
    for (int c = 0; c < 32; ++c) {
      float dc = __shfl(a[c], c);      // fully-updated diagonal (= L_cc^2)
      ls += logf(dc);
      float s_ = sqrtf(dc);
      a[c] = a[c] / s_;
#pragma unroll
      for (int k = c + 1; k < 32; ++k)
        a[k] -= a[c] * __shfl(a[c], k);
    }
    if (tid < 32) {
#pragma unroll
      for (int c = 0; c < 32; ++c) sm[o + r][o + c] = a[c];
    }
    if (tid == 0) logacc += ls;
  }
}

// ---------- right-looking panel step: factor 64x64 diag block at (s,s) + TRSM rows below ----------
__global__ __launch_bounds__(512) void k_panel(float* La, float* Lw1, float* __restrict__ ld, int s) {
  float* A = (blockIdx.x == 0) ? La : Lw1;
  const int j0 = s * 64;
  int tid = threadIdx.x;
  __shared__ float sm[64][65];
  __shared__ float smT[64][68];
  __shared__ float rinv[64];
  float logacc = 0.f;

  // load 64x64 diag block
  for (int i = tid; i < 4096; i += 512) {
    int r = i >> 6, c = i & 63;
    sm[r][c] = A[(size_t)(j0 + r) * K_N + j0 + c];
  }
  __syncthreads();

  // factor A11 (32x32)
  factor32(sm, 0, tid, logacc);
  __syncthreads();

  // TRSM A21 (rows 32..63 vs L11)
  if (tid < 32) {
    int r = 32 + tid;
    float x[32];
#pragma unroll
    for (int c = 0; c < 32; ++c) x[c] = sm[r][c];
#pragma unroll
    for (int c = 0; c < 32; ++c) {
      x[c] = x[c] / sm[c][c];
#pragma unroll
      for (int k = c + 1; k < 32; ++k)
        x[k] -= x[c] * sm[k][c];
    }
#pragma unroll
    for (int c = 0; c < 32; ++c) sm[r][c] = x[c];
  }
  __syncthreads();

  // A22 -= A21 @ A21^T  (full 32x32 for symmetry)
  for (int i = tid; i < 1024; i += 512) {
    int r = 32 + (i >> 5), c = 32 + (i & 31);
    float accv = 0.f;
#pragma unroll
    for (int k = 0; k < 32; ++k) accv += sm[r][k] * sm[c][k];
    sm[r][c] -= accv;
  }
  __syncthreads();

  // factor A22
  factor32(sm, 32, tid, logacc);
  __syncthreads();

  // build transposed L (smT[c][k] = L[k][c]) + diag reciprocals
  for (int i = tid; i < 4096; i += 512) {
    int r = i >> 6, c = i & 63;
    smT[c][r] = sm[r][c];
  }
  if (tid < 64) rinv[tid] = 1.0f / sm[tid][tid];
  __syncthreads();

  // big TRSM: rows j0+64 .. 511, one row per thread
  int rrow = j0 + 64 + tid;
  if (rrow < K_N) {
    float x[64];
#pragma unroll
    for (int q = 0; q < 16; ++q) {
      float4 f = *(const float4*)&A[(size_t)rrow * K_N + j0 + 4 * q];
      x[4 * q] = f.x; x[4 * q + 1] = f.y; x[4 * q + 2] = f.z; x[4 * q + 3] = f.w;
    }
#pragma unroll
    for (int c = 0; c < 64; ++c) {
      x[c] *= rinv[c];
#pragma unroll
      for (int k = c + 1; k < 64; ++k)
        x[k] -= x[c] * smT[c][k];
    }
#pragma unroll
    for (int q = 0; q < 16; ++q) {
      float4 f;
      f.x = x[4 * q]; f.y = x[4 * q + 1]; f.z = x[4 * q + 2]; f.w = x[4 * q + 3];
      *(float4*)&A[(size_t)rrow * K_N + j0 + 4 * q] = f;
    }
  }

  // write diag block back
  for (int i = tid; i < 4096; i += 512) {
    int r = i >> 6, c = i & 63;
    A[(size_t)(j0 + r) * K_N + j0 + c] = sm[r][c];
  }
  if (tid == 0) ld[blockIdx.x * 8 + s] = logacc;
}

// ---------- trailing update: C[bi,bj] -= Lp[bi] @ Lp[bj]^T  (rank-64) ----------
__global__ __launch_bounds__(256) void k_update(float* La, float* Lw1, int s) {
  float* A = (blockIdx.y == 0) ? La : Lw1;
  int nt = 7 - s;
  int p = blockIdx.x;
  int bj = 0;
  while (p >= nt - bj) { p -= nt - bj; ++bj; }
  int bi = bj + p;
  int r0g = (s + 1 + bi) * 64, c0g = (s + 1 + bj) * 64, k0g = s * 64;

  __shared__ float As[64][68];   // As[k][r] = L[r0g+r][k0g+k]
  __shared__ float Bs[64][68];   // Bs[k][c] = L[c0g+c][k0g+k]
  int tid = threadIdx.x;
  for (int i = tid; i < 1024; i += 256) {
    int r = i >> 4, kq = (i & 15) << 2;
    float4 f = *(const float4*)&A[(size_t)(r0g + r) * K_N + k0g + kq];
    As[kq + 0][r] = f.x; As[kq + 1][r] = f.y; As[kq + 2][r] = f.z; As[kq + 3][r] = f.w;
    float4 g = *(const float4*)&A[(size_t)(c0g + r) * K_N + k0g + kq];
    Bs[kq + 0][r] = g.x; Bs[kq + 1][r] = g.y; Bs[kq + 2][r] = g.z; Bs[kq + 3][r] = g.w;
  }
  __syncthreads();

  int r0 = (tid >> 4) * 4, c0 = (tid & 15) * 4;
  float acc[4][4];
#pragma unroll
  for (int i = 0; i < 4; ++i)
#pragma unroll
    for (int j = 0; j < 4; ++j) acc[i][j] = 0.f;
#pragma unroll 4
  for (int k = 0; k < 64; ++k) {
    float4 av = *(const float4*)&As[k][r0];
    float4 bv = *(const float4*)&Bs[k][c0];
    acc[0][0] += av.x * bv.x; acc[0][1] += av.x * bv.y; acc[0][2] += av.x * bv.z; acc[0][3] += av.x * bv.w;
    acc[1][0] += av.y * bv.x; acc[1][1] += av.y * bv.y; acc[1][2] += av.y * bv.z; acc[1][3] += av.y * bv.w;
    acc[2][0] += av.z * bv.x; acc[2][1] += av.z * bv.y; acc[2][2] += av.z * bv.z; acc[2][3] += av.z * bv.w;
    acc[3][0] += av.w * bv.x; acc[3][1] += av.w * bv.y; acc[3][2] += av.w * bv.z; acc[3][3] += av.w * bv.w;
  }
#pragma unroll
  for (int i = 0; i < 4; ++i) {
    float* cp = &A[(size_t)(r0g + r0 + i) * K_N + c0g + c0];
#pragma unroll
    for (int j = 0; j < 4; ++j) cp[j] = cp[j] - acc[i][j];
  }
}

// ---------- combine ----------
__global__ void k_combine(const float* __restrict__ ld, const float* __restrict__ tr, float* __restrict__ out) {
  float l0 = 0.f, l1 = 0.f;
#pragma unroll
  for (int s = 0; s < 8; ++s) { l0 += ld[s]; l1 += ld[8 + s]; }
  out[0] = -l0 - l1 - (float)K_N + tr[0];
}

extern "C" void kernel_launch(void* const* d_in, const int* in_sizes, int n_in,
                              void* d_out, int out_size, void* d_ws, size_t ws_size,
                              hipStream_t stream) {
  const float* X  = (const float*)d_in[0];   // inputs  [V,128]
  const float* T  = (const float*)d_in[1];   // targets [K,K]
  const int*   ei = (const int*)d_in[2];     // edge_index [2,E]
  const float* P  = (const float*)d_in[3];   // pmat [K,V]
  float* out = (float*)d_out;
  char* ws = (char*)d_ws;

  // workspace layout (bytes)
  int*      cnt  = (int*)(ws + 0);
  float*    tr   = (float*)(ws + 16);
  float*    ld   = (float*)(ws + 32);            // 16 floats
  float*    deg  = (float*)(ws + 256);           // V floats -> 33024
  float*    PT   = (float*)(ws + 33024);         // V*K (16 MB) -> 16810240
  float*    Y    = (float*)(ws + 16810240);      // V*K (16 MB) -> 33587456
  int*      si   = (int*)(ws + 33587456);        // 32768 ints -> 33718528
  int*      sj   = (int*)(ws + 33718528);        // 32768 ints -> 33849600
  float*    sw   = (float*)(ws + 33849600);      // 32768 floats -> 33980672
  unsigned* htab = (unsigned*)(ws + 33980672);   // 65536 u32 (256 KB) -> 34242816
  float*    La   = (float*)(ws + 34242816);      // K*K (1 MB) -> 35291392
  float*    Lw1  = (float*)(ws + 35291392);      // K*K (1 MB) -> 36339968

  hipMemsetAsync(ws, 0, 33024, stream);                        // cnt, tr, ld, deg
  hipMemsetAsync(Y, 0, (size_t)V_N * K_N * sizeof(float), stream);
  hipMemsetAsync(htab, 0xFF, 65536 * sizeof(unsigned), stream);

  k_transpose<<<dim3(V_N / 32, K_N / 32), dim3(32, 8), 0, stream>>>(P, PT);
  k_edge<<<E_N / 16, 256, 0, stream>>>(X, ei, deg, cnt, si, sj, sw, htab);
  k_scatter<<<2048, 128, 0, stream>>>(cnt, si, sj, sw, PT, Y);
  k_init<<<K_N * K_N / 256, 256, 0, stream>>>(La);
  k_gemm<<<dim3(8, 8, 8), 256, 0, stream>>>(P, PT, Y, deg, La);
  k_trace<<<K_N * K_N / 256, 256, 0, stream>>>(La, T, tr);

  hipMemcpyAsync(Lw1, T, (size_t)K_N * K_N * sizeof(float), hipMemcpyDeviceToDevice, stream);
  for (int s = 0; s < 8; ++s) {
    k_panel<<<2, 512, 0, stream>>>(La, Lw1, ld, s);
    int nt = 7 - s;
    if (nt > 0) k_update<<<dim3(nt * (nt + 1) / 2, 2), 256, 0, stream>>>(La, Lw1, s);
  }
  k_combine<<<1, 1, 0, stream>>>(ld, tr, out);
}

// Round 4
// 637.137 us; speedup vs baseline: 1.4452x; 1.1697x over previous
//
#include <hip/hip_runtime.h>
#include <math.h>

#define V_N 8192
#define D_F 128
#define E_N 262144
#define K_N 512
#define DMAXF 0.5f
#define EPSW 1e-8f
#define EPSL 1e-5f
#define MAX_SE 16384
#define NZ_SYRK 8

// ---------- transpose pmat (K x V) -> PT (V x K) ----------
__global__ __launch_bounds__(256) void k_transpose(const float* __restrict__ P, float* __restrict__ PT) {
  __shared__ float tile[32][33];
  int v0 = blockIdx.x * 32, k0 = blockIdx.y * 32;
  int tx = threadIdx.x, ty = threadIdx.y;
#pragma unroll
  for (int i = 0; i < 4; ++i)
    tile[ty + i * 8][tx] = P[(size_t)(k0 + ty + i * 8) * V_N + v0 + tx];
  __syncthreads();
#pragma unroll
  for (int i = 0; i < 4; ++i)
    PT[(size_t)(v0 + ty + i * 8) * K_N + k0 + tx] = tile[tx][ty + i * 8];
}

// ---------- per-edge distance, strong-edge dedup + compaction (weak edges dropped: O(1e-7) effect) ----------
__global__ __launch_bounds__(256) void k_edge(const float* __restrict__ X, const int* __restrict__ ei,
                                              int* __restrict__ cnt,
                                              int* __restrict__ si, int* __restrict__ sj,
                                              float* __restrict__ sw, unsigned* __restrict__ htab) {
  int t = blockIdx.x * 256 + threadIdx.x;
  int e = t >> 4, lane = t & 15;           // 16 lanes per edge
  int i = ei[e], j = ei[E_N + e];
  const float4* xi = (const float4*)(X + (size_t)i * D_F);
  const float4* xj = (const float4*)(X + (size_t)j * D_F);
  float4 a0 = xi[lane * 2], a1 = xi[lane * 2 + 1];
  float4 b0 = xj[lane * 2], b1 = xj[lane * 2 + 1];
  float d = 0.f, dx;
  dx = a0.x - b0.x; d += dx * dx;
  dx = a0.y - b0.y; d += dx * dx;
  dx = a0.z - b0.z; d += dx * dx;
  dx = a0.w - b0.w; d += dx * dx;
  dx = a1.x - b1.x; d += dx * dx;
  dx = a1.y - b1.y; d += dx * dx;
  dx = a1.z - b1.z; d += dx * dx;
  dx = a1.w - b1.w; d += dx * dx;
  d += __shfl_xor(d, 1);
  d += __shfl_xor(d, 2);
  d += __shfl_xor(d, 4);
  d += __shfl_xor(d, 8);
  if (lane == 0 && d <= DMAXF) {
    float w = expf(-d);
    unsigned a = (unsigned)min(i, j), b = (unsigned)max(i, j);
    unsigned key = a * 8192u + b;          // key==0 impossible (a<b)
    unsigned h = (key * 2654435761u) >> 16;
    bool isnew = false;
    for (int probe = 0; probe < 65536; ++probe) {
      unsigned slot = (h + (unsigned)probe) & 65535u;
      unsigned prev = atomicCAS(&htab[slot], 0u, key);
      if (prev == 0u) { isnew = true; break; }
      if (prev == key) break;              // duplicate pair -> reference counts it once
    }
    if (isnew) {
      int p = atomicAdd(cnt, 1);
      if (p < MAX_SE) { si[p] = i; sj[p] = j; sw[p] = w; }
    }
  }
}

// ---------- La(lower) += Q^T Q + eps*I, Q rows = sqrt(w)*(PT[i]-PT[j]), gathered on the fly ----------
__global__ __launch_bounds__(256) void k_syrk(const int* __restrict__ cnt, const int* __restrict__ si,
                                              const int* __restrict__ sj, const float* __restrict__ sw,
                                              const float* __restrict__ PT, float* __restrict__ La) {
  // map blockIdx.x -> lower-tri tile pair (bi >= bj) of the 8x8 tile grid
  int p = blockIdx.x, bj = 0;
  while (p >= 8 - bj) { p -= 8 - bj; ++bj; }
  int bi = bj + p;
  int r0g = bi * 64, c0g = bj * 64;
  int m = min(*cnt, MAX_SE);
  int chunk = (m + NZ_SYRK - 1) / NZ_SYRK;
  int e0 = blockIdx.y * chunk;
  int e1 = min(m, e0 + chunk);

  __shared__ float As[16][68];
  __shared__ float Bs[16][68];
  int tid = threadIdx.x;
  int le = tid >> 4, f = tid & 15;   // edge slot, float4 slot
  int r0 = (tid >> 4) * 4, c0 = (tid & 15) * 4;
  float acc[4][4];
#pragma unroll
  for (int i = 0; i < 4; ++i)
#pragma unroll
    for (int j = 0; j < 4; ++j) acc[i][j] = 0.f;

  for (int es = e0; es < e1; es += 16) {
    int e = es + le;
    float4 qa = make_float4(0.f, 0.f, 0.f, 0.f);
    float4 qb = make_float4(0.f, 0.f, 0.f, 0.f);
    if (e < e1) {
      int i = si[e], j = sj[e];
      float w = sqrtf(sw[e]);
      const float* pi = &PT[(size_t)i * K_N];
      const float* pj = &PT[(size_t)j * K_N];
      float4 ai = *(const float4*)(pi + r0g + f * 4);
      float4 aj = *(const float4*)(pj + r0g + f * 4);
      qa.x = w * (ai.x - aj.x); qa.y = w * (ai.y - aj.y);
      qa.z = w * (ai.z - aj.z); qa.w = w * (ai.w - aj.w);
      if (bi != bj) {
        float4 ci = *(const float4*)(pi + c0g + f * 4);
        float4 cj = *(const float4*)(pj + c0g + f * 4);
        qb.x = w * (ci.x - cj.x); qb.y = w * (ci.y - cj.y);
        qb.z = w * (ci.z - cj.z); qb.w = w * (ci.w - cj.w);
      } else {
        qb = qa;
      }
    }
    __syncthreads();                 // protect previous iteration's LDS reads
    *(float4*)&As[le][f * 4] = qa;
    *(float4*)&Bs[le][f * 4] = qb;
    __syncthreads();
#pragma unroll
    for (int k = 0; k < 16; ++k) {
      float4 av = *(const float4*)&As[k][r0];
      float4 bv = *(const float4*)&Bs[k][c0];
      acc[0][0] += av.x * bv.x; acc[0][1] += av.x * bv.y; acc[0][2] += av.x * bv.z; acc[0][3] += av.x * bv.w;
      acc[1][0] += av.y * bv.x; acc[1][1] += av.y * bv.y; acc[1][2] += av.y * bv.z; acc[1][3] += av.y * bv.w;
      acc[2][0] += av.z * bv.x; acc[2][1] += av.z * bv.y; acc[2][2] += av.z * bv.z; acc[2][3] += av.z * bv.w;
      acc[3][0] += av.w * bv.x; acc[3][1] += av.w * bv.y; acc[3][2] += av.w * bv.z; acc[3][3] += av.w * bv.w;
    }
  }
  bool addeps = (blockIdx.y == 0) && (bi == bj);
#pragma unroll
  for (int i = 0; i < 4; ++i)
#pragma unroll
    for (int j = 0; j < 4; ++j) {
      float v = acc[i][j];
      if (addeps && (r0 + i == c0 + j)) v += EPSL;
      atomicAdd(&La[(size_t)(r0g + r0 + i) * K_N + c0g + c0 + j], v);
    }
}

// ---------- trace = sum(La .* T^T) via symmetry: diag + 2*lower (T symmetric, La lower-only) ----------
__global__ __launch_bounds__(256) void k_trace(const float* __restrict__ La, const float* __restrict__ T,
                                               float* __restrict__ tr) {
  int idx = blockIdx.x * 256 + threadIdx.x;
  int r = idx >> 9, c = idx & 511;
  float v = 0.f;
  if (r >= c) {
    float scale = (r == c) ? 1.f : 2.f;
    v = scale * La[idx] * T[idx];
  }
  v += __shfl_down(v, 32); v += __shfl_down(v, 16); v += __shfl_down(v, 8);
  v += __shfl_down(v, 4);  v += __shfl_down(v, 2);  v += __shfl_down(v, 1);
  if ((threadIdx.x & 63) == 0) atomicAdd(tr, v);
}

// ---------- in-register 32x32 Cholesky factor of sm[o:o+32][o:o+32] by wave 0 ----------
__device__ __forceinline__ void factor32(float (*sm)[65], int o, int tid, float& logacc) {
  if (tid < 64) {
    int r = tid & 31;
    float a[32];
#pragma unroll
    for (int c = 0; c < 32; ++c) a[c] = sm[o + r][o + c];
    float ls = 0.f;
#pragma unroll
    for (int c = 0; c < 32; ++c) {
      float dc = __shfl(a[c], c);      // fully-updated diagonal (= L_cc^2)
      ls += logf(dc);
      float s_ = sqrtf(dc);
      a[c] = a[c] / s_;
#pragma unroll
      for (int k = c + 1; k < 32; ++k)
        a[k] -= a[c] * __shfl(a[c], k);
    }
    if (tid < 32) {
#pragma unroll
      for (int c = 0; c < 32; ++c) sm[o + r][o + c] = a[c];
    }
    if (tid == 0) logacc += ls;
  }
}

// ---------- right-looking panel step: factor 64x64 diag block at (s,s) + TRSM rows below ----------
__global__ __launch_bounds__(512) void k_panel(float* La, float* Lw1, float* __restrict__ ld, int s) {
  float* A = (blockIdx.x == 0) ? La : Lw1;
  const int j0 = s * 64;
  int tid = threadIdx.x;
  __shared__ float sm[64][65];
  __shared__ float smT[64][68];
  __shared__ float rinv[64];
  float logacc = 0.f;

  // load 64x64 diag block
  for (int i = tid; i < 4096; i += 512) {
    int r = i >> 6, c = i & 63;
    sm[r][c] = A[(size_t)(j0 + r) * K_N + j0 + c];
  }
  __syncthreads();

  // factor A11 (32x32)
  factor32(sm, 0, tid, logacc);
  __syncthreads();

  // TRSM A21 (rows 32..63 vs L11)
  if (tid < 32) {
    int r = 32 + tid;
    float x[32];
#pragma unroll
    for (int c = 0; c < 32; ++c) x[c] = sm[r][c];
#pragma unroll
    for (int c = 0; c < 32; ++c) {
      x[c] = x[c] / sm[c][c];
#pragma unroll
      for (int k = c + 1; k < 32; ++k)
        x[k] -= x[c] * sm[k][c];
    }
#pragma unroll
    for (int c = 0; c < 32; ++c) sm[r][c] = x[c];
  }
  __syncthreads();

  // A22 -= A21 @ A21^T  (full 32x32 for symmetry)
  for (int i = tid; i < 1024; i += 512) {
    int r = 32 + (i >> 5), c = 32 + (i & 31);
    float accv = 0.f;
#pragma unroll
    for (int k = 0; k < 32; ++k) accv += sm[r][k] * sm[c][k];
    sm[r][c] -= accv;
  }
  __syncthreads();

  // factor A22
  factor32(sm, 32, tid, logacc);
  __syncthreads();

  // build transposed L (smT[c][k] = L[k][c]) + diag reciprocals
  for (int i = tid; i < 4096; i += 512) {
    int r = i >> 6, c = i & 63;
    smT[c][r] = sm[r][c];
  }
  if (tid < 64) rinv[tid] = 1.0f / sm[tid][tid];
  __syncthreads();

  // big TRSM: rows j0+64 .. 511, one row per thread
  int rrow = j0 + 64 + tid;
  if (rrow < K_N) {
    float x[64];
#pragma unroll
    for (int q = 0; q < 16; ++q) {
      float4 f = *(const float4*)&A[(size_t)rrow * K_N + j0 + 4 * q];
      x[4 * q] = f.x; x[4 * q + 1] = f.y; x[4 * q + 2] = f.z; x[4 * q + 3] = f.w;
    }
#pragma unroll
    for (int c = 0; c < 64; ++c) {
      x[c] *= rinv[c];
#pragma unroll
      for (int k = c + 1; k < 64; ++k)
        x[k] -= x[c] * smT[c][k];
    }
#pragma unroll
    for (int q = 0; q < 16; ++q) {
      float4 f;
      f.x = x[4 * q]; f.y = x[4 * q + 1]; f.z = x[4 * q + 2]; f.w = x[4 * q + 3];
      *(float4*)&A[(size_t)rrow * K_N + j0 + 4 * q] = f;
    }
  }

  // write diag block back
  for (int i = tid; i < 4096; i += 512) {
    int r = i >> 6, c = i & 63;
    A[(size_t)(j0 + r) * K_N + j0 + c] = sm[r][c];
  }
  if (tid == 0) ld[blockIdx.x * 8 + s] = logacc;
}

// ---------- trailing update: C[bi,bj] -= Lp[bi] @ Lp[bj]^T  (rank-64) ----------
__global__ __launch_bounds__(256) void k_update(float* La, float* Lw1, int s) {
  float* A = (blockIdx.y == 0) ? La : Lw1;
  int nt = 7 - s;
  int p = blockIdx.x;
  int bj = 0;
  while (p >= nt - bj) { p -= nt - bj; ++bj; }
  int bi = bj + p;
  int r0g = (s + 1 + bi) * 64, c0g = (s + 1 + bj) * 64, k0g = s * 64;

  __shared__ float As[64][68];   // As[k][r] = L[r0g+r][k0g+k]
  __shared__ float Bs[64][68];   // Bs[k][c] = L[c0g+c][k0g+k]
  int tid = threadIdx.x;
  for (int i = tid; i < 1024; i += 256) {
    int r = i >> 4, kq = (i & 15) << 2;
    float4 f = *(const float4*)&A[(size_t)(r0g + r) * K_N + k0g + kq];
    As[kq + 0][r] = f.x; As[kq + 1][r] = f.y; As[kq + 2][r] = f.z; As[kq + 3][r] = f.w;
    float4 g = *(const float4*)&A[(size_t)(c0g + r) * K_N + k0g + kq];
    Bs[kq + 0][r] = g.x; Bs[kq + 1][r] = g.y; Bs[kq + 2][r] = g.z; Bs[kq + 3][r] = g.w;
  }
  __syncthreads();

  int r0 = (tid >> 4) * 4, c0 = (tid & 15) * 4;
  float acc[4][4];
#pragma unroll
  for (int i = 0; i < 4; ++i)
#pragma unroll
    for (int j = 0; j < 4; ++j) acc[i][j] = 0.f;
#pragma unroll 4
  for (int k = 0; k < 64; ++k) {
    float4 av = *(const float4*)&As[k][r0];
    float4 bv = *(const float4*)&Bs[k][c0];
    acc[0][0] += av.x * bv.x; acc[0][1] += av.x * bv.y; acc[0][2] += av.x * bv.z; acc[0][3] += av.x * bv.w;
    acc[1][0] += av.y * bv.x; acc[1][1] += av.y * bv.y; acc[1][2] += av.y * bv.z; acc[1][3] += av.y * bv.w;
    acc[2][0] += av.z * bv.x; acc[2][1] += av.z * bv.y; acc[2][2] += av.z * bv.z; acc[2][3] += av.z * bv.w;
    acc[3][0] += av.w * bv.x; acc[3][1] += av.w * bv.y; acc[3][2] += av.w * bv.z; acc[3][3] += av.w * bv.w;
  }
#pragma unroll
  for (int i = 0; i < 4; ++i) {
    float* cp = &A[(size_t)(r0g + r0 + i) * K_N + c0g + c0];
#pragma unroll
    for (int j = 0; j < 4; ++j) cp[j] = cp[j] - acc[i][j];
  }
}

// ---------- combine ----------
__global__ void k_combine(const float* __restrict__ ld, const float* __restrict__ tr, float* __restrict__ out) {
  float l0 = 0.f, l1 = 0.f;
#pragma unroll
  for (int s = 0; s < 8; ++s) { l0 += ld[s]; l1 += ld[8 + s]; }
  out[0] = -l0 - l1 - (float)K_N + tr[0];
}

extern "C" void kernel_launch(void* const* d_in, const int* in_sizes, int n_in,
                              void* d_out, int out_size, void* d_ws, size_t ws_size,
                              hipStream_t stream) {
  const float* X  = (const float*)d_in[0];   // inputs  [V,128]
  const float* T  = (const float*)d_in[1];   // targets [K,K]
  const int*   ei = (const int*)d_in[2];     // edge_index [2,E]
  const float* P  = (const float*)d_in[3];   // pmat [K,V]
  float* out = (float*)d_out;
  char* ws = (char*)d_ws;

  // workspace layout (bytes); [0, 1314816) is one contiguous zero-memset region
  int*      cnt  = (int*)(ws + 0);
  float*    tr   = (float*)(ws + 16);
  float*    ld   = (float*)(ws + 32);            // 16 floats
  unsigned* htab = (unsigned*)(ws + 4096);       // 65536 u32 (256 KB) -> 266240
  float*    La   = (float*)(ws + 266240);        // K*K (1 MB) -> 1314816  (zeroed; lower-tri filled)
  float*    Lw1  = (float*)(ws + 1314816);       // K*K (1 MB) -> 2363392  (memcpy'd from T)
  int*      si   = (int*)(ws + 2363392);         // 16384 ints -> 2428928
  int*      sj   = (int*)(ws + 2428928);         // 16384 ints -> 2494464
  float*    sw   = (float*)(ws + 2494464);       // 16384 floats -> 2560000
  float*    PT   = (float*)(ws + 2560000);       // V*K floats (16 MB) -> 19337216

  hipMemsetAsync(ws, 0, 1314816, stream);        // cnt, tr, ld, htab, La

  k_transpose<<<dim3(V_N / 32, K_N / 32), dim3(32, 8), 0, stream>>>(P, PT);
  k_edge<<<E_N / 16, 256, 0, stream>>>(X, ei, cnt, si, sj, sw, htab);
  k_syrk<<<dim3(36, NZ_SYRK), 256, 0, stream>>>(cnt, si, sj, sw, PT, La);
  k_trace<<<K_N * K_N / 256, 256, 0, stream>>>(La, T, tr);

  hipMemcpyAsync(Lw1, T, (size_t)K_N * K_N * sizeof(float), hipMemcpyDeviceToDevice, stream);
  for (int s = 0; s < 8; ++s) {
    k_panel<<<2, 512, 0, stream>>>(La, Lw1, ld, s);
    int nt = 7 - s;
    if (nt > 0) k_update<<<dim3(nt * (nt + 1) / 2, 2), 256, 0, stream>>>(La, Lw1, s);
  }
  k_combine<<<1, 1, 0, stream>>>(ld, tr, out);
}

// Round 5
// 553.023 us; speedup vs baseline: 1.6650x; 1.1521x over previous
//
#include <hip/hip_runtime.h>
#include <math.h>

#define V_N 8192
#define D_F 128
#define E_N 262144
#define K_N 512
#define DMAXF 0.5f
#define EPSW 1e-8f
#define EPSL 1e-5f
#define MAX_SE 16384
#define NZ_SYRK 24

#define NB_TR 4096
#define NB_ED (E_N / 16)
#define NB_CP 256

// ---------- fused pre-pass: transpose pmat -> PT | edge weights+dedup | Lw1 <- T ----------
__global__ __launch_bounds__(256) void k_pre(const float* __restrict__ P, float* __restrict__ PT,
                                             const float* __restrict__ X, const int* __restrict__ ei,
                                             int* __restrict__ cnt, int* __restrict__ si,
                                             int* __restrict__ sj, float* __restrict__ sw,
                                             unsigned* __restrict__ htab,
                                             const float* __restrict__ T, float* __restrict__ Lw1) {
  __shared__ float tile[32][33];
  int b = blockIdx.x;
  if (b < NB_TR) {
    // transpose P (K x V) -> PT (V x K), 32x32 tiles
    int v0 = (b & 255) * 32, k0 = (b >> 8) * 32;
    int tx = threadIdx.x & 31, ty = threadIdx.x >> 5;
#pragma unroll
    for (int i = 0; i < 4; ++i)
      tile[ty + i * 8][tx] = P[(size_t)(k0 + ty + i * 8) * V_N + v0 + tx];
    __syncthreads();
#pragma unroll
    for (int i = 0; i < 4; ++i)
      PT[(size_t)(v0 + ty + i * 8) * K_N + k0 + tx] = tile[tx][ty + i * 8];
  } else if (b < NB_TR + NB_ED) {
    // per-edge distance, strong-edge dedup + compaction (weak edges dropped: O(1e-7) effect)
    int t = (b - NB_TR) * 256 + threadIdx.x;
    int e = t >> 4, lane = t & 15;           // 16 lanes per edge
    int i = ei[e], j = ei[E_N + e];
    const float4* xi = (const float4*)(X + (size_t)i * D_F);
    const float4* xj = (const float4*)(X + (size_t)j * D_F);
    float4 a0 = xi[lane * 2], a1 = xi[lane * 2 + 1];
    float4 b0 = xj[lane * 2], b1 = xj[lane * 2 + 1];
    float d = 0.f, dx;
    dx = a0.x - b0.x; d += dx * dx;
    dx = a0.y - b0.y; d += dx * dx;
    dx = a0.z - b0.z; d += dx * dx;
    dx = a0.w - b0.w; d += dx * dx;
    dx = a1.x - b1.x; d += dx * dx;
    dx = a1.y - b1.y; d += dx * dx;
    dx = a1.z - b1.z; d += dx * dx;
    dx = a1.w - b1.w; d += dx * dx;
    d += __shfl_xor(d, 1);
    d += __shfl_xor(d, 2);
    d += __shfl_xor(d, 4);
    d += __shfl_xor(d, 8);
    if (lane == 0 && d <= DMAXF) {
      float w = expf(-d);
      unsigned a = (unsigned)min(i, j), bb = (unsigned)max(i, j);
      unsigned key = a * 8192u + bb;         // key==0 impossible (a<b)
      unsigned h = (key * 2654435761u) >> 16;
      bool isnew = false;
      for (int probe = 0; probe < 65536; ++probe) {
        unsigned slot = (h + (unsigned)probe) & 65535u;
        unsigned prev = atomicCAS(&htab[slot], 0u, key);
        if (prev == 0u) { isnew = true; break; }
        if (prev == key) break;              // duplicate pair -> reference counts it once
      }
      if (isnew) {
        int p = atomicAdd(cnt, 1);
        if (p < MAX_SE) { si[p] = i; sj[p] = j; sw[p] = w; }
      }
    }
  } else {
    // Lw1 <- T (float4 copy)
    int idx = (b - NB_TR - NB_ED) * 256 + threadIdx.x;
    ((float4*)Lw1)[idx] = ((const float4*)T)[idx];
  }
}

// ---------- La(lower) += Q^T Q + eps*I, Q rows = sqrt(w)*(PT[i]-PT[j]); fused trace epilogue ----------
__global__ __launch_bounds__(256) void k_syrk(const int* __restrict__ cnt, const int* __restrict__ si,
                                              const int* __restrict__ sj, const float* __restrict__ sw,
                                              const float* __restrict__ PT, float* __restrict__ La,
                                              const float* __restrict__ T, float* __restrict__ tr) {
  // map blockIdx.x -> lower-tri tile pair (bi >= bj) of the 8x8 tile grid
  int p = blockIdx.x, bj = 0;
  while (p >= 8 - bj) { p -= 8 - bj; ++bj; }
  int bi = bj + p;
  int r0g = bi * 64, c0g = bj * 64;
  int m = min(*cnt, MAX_SE);
  int chunk = (m + NZ_SYRK - 1) / NZ_SYRK;
  int e0 = blockIdx.y * chunk;
  int e1 = min(m, e0 + chunk);

  __shared__ float As[16][68];
  __shared__ float Bs[16][68];
  int tid = threadIdx.x;
  int le = tid >> 4, f = tid & 15;   // edge slot, float4 slot
  int r0 = (tid >> 4) * 4, c0 = (tid & 15) * 4;
  float acc[4][4];
#pragma unroll
  for (int i = 0; i < 4; ++i)
#pragma unroll
    for (int j = 0; j < 4; ++j) acc[i][j] = 0.f;

  // prefetched edge state
  float w_ = 0.f;
  float4 ai = make_float4(0.f, 0.f, 0.f, 0.f), aj = ai, ci = ai, cj = ai;
  {
    int e = e0 + le;
    if (e < e1) {
      int i = si[e], j = sj[e];
      w_ = sw[e];
      const float* pi = &PT[(size_t)i * K_N];
      const float* pj = &PT[(size_t)j * K_N];
      ai = *(const float4*)(pi + r0g + f * 4);
      aj = *(const float4*)(pj + r0g + f * 4);
      if (bi != bj) {
        ci = *(const float4*)(pi + c0g + f * 4);
        cj = *(const float4*)(pj + c0g + f * 4);
      }
    }
  }

  for (int es = e0; es < e1; es += 16) {
    float sq = sqrtf(w_);
    float4 qa, qb;
    qa.x = sq * (ai.x - aj.x); qa.y = sq * (ai.y - aj.y);
    qa.z = sq * (ai.z - aj.z); qa.w = sq * (ai.w - aj.w);
    if (bi != bj) {
      qb.x = sq * (ci.x - cj.x); qb.y = sq * (ci.y - cj.y);
      qb.z = sq * (ci.z - cj.z); qb.w = sq * (ci.w - cj.w);
    } else {
      qb = qa;
    }
    __syncthreads();                 // protect previous iteration's LDS reads
    *(float4*)&As[le][f * 4] = qa;
    *(float4*)&Bs[le][f * 4] = qb;
    __syncthreads();

    // prefetch next 16-edge group (hidden under the FMA block below)
    {
      int e = es + 16 + le;
      w_ = 0.f;
      if (e < e1) {
        int i = si[e], j = sj[e];
        w_ = sw[e];
        const float* pi = &PT[(size_t)i * K_N];
        const float* pj = &PT[(size_t)j * K_N];
        ai = *(const float4*)(pi + r0g + f * 4);
        aj = *(const float4*)(pj + r0g + f * 4);
        if (bi != bj) {
          ci = *(const float4*)(pi + c0g + f * 4);
          cj = *(const float4*)(pj + c0g + f * 4);
        }
      }
    }

#pragma unroll
    for (int k = 0; k < 16; ++k) {
      float4 av = *(const float4*)&As[k][r0];
      float4 bv = *(const float4*)&Bs[k][c0];
      acc[0][0] += av.x * bv.x; acc[0][1] += av.x * bv.y; acc[0][2] += av.x * bv.z; acc[0][3] += av.x * bv.w;
      acc[1][0] += av.y * bv.x; acc[1][1] += av.y * bv.y; acc[1][2] += av.y * bv.z; acc[1][3] += av.y * bv.w;
      acc[2][0] += av.z * bv.x; acc[2][1] += av.z * bv.y; acc[2][2] += av.z * bv.z; acc[2][3] += av.z * bv.w;
      acc[3][0] += av.w * bv.x; acc[3][1] += av.w * bv.y; acc[3][2] += av.w * bv.z; acc[3][3] += av.w * bv.w;
    }
  }

  bool addeps = (blockIdx.y == 0) && (bi == bj);
  float tdot = 0.f;
#pragma unroll
  for (int i = 0; i < 4; ++i)
#pragma unroll
    for (int j = 0; j < 4; ++j) {
      float v = acc[i][j];
      int rg = r0g + r0 + i, cg = c0g + c0 + j;
      if (addeps && rg == cg) v += EPSL;
      atomicAdd(&La[(size_t)rg * K_N + cg], v);
      // fused trace: sum(La .* T^T) via symmetry = diag + 2*strict-lower (T symmetric)
      float sc = (bi != bj) ? 2.f : (rg == cg ? 1.f : (rg > cg ? 2.f : 0.f));
      if (sc != 0.f) tdot += sc * v * T[(size_t)rg * K_N + cg];
    }
  tdot += __shfl_down(tdot, 32); tdot += __shfl_down(tdot, 16); tdot += __shfl_down(tdot, 8);
  tdot += __shfl_down(tdot, 4);  tdot += __shfl_down(tdot, 2);  tdot += __shfl_down(tdot, 1);
  if ((tid & 63) == 0) atomicAdd(tr, tdot);
}

// ---------- in-register 32x32 Cholesky factor of sm[o:o+32][o:o+32] by wave 0 ----------
__device__ __forceinline__ void factor32(float (*sm)[65], int o, int tid, float& logacc) {
  if (tid < 64) {
    int r = tid & 31;
    float a[32];
#pragma unroll
    for (int c = 0; c < 32; ++c) a[c] = sm[o + r][o + c];
    float ls = 0.f;
#pragma unroll
    for (int c = 0; c < 32; ++c) {
      float dc = __shfl(a[c], c);      // fully-updated diagonal (= L_cc^2)
      ls += logf(dc);
      float s_ = sqrtf(dc);
      a[c] = a[c] / s_;
#pragma unroll
      for (int k = c + 1; k < 32; ++k)
        a[k] -= a[c] * __shfl(a[c], k);
    }
    if (tid < 32) {
#pragma unroll
      for (int c = 0; c < 32; ++c) sm[o + r][o + c] = a[c];
    }
    if (tid == 0) logacc += ls;
  }
}

// ---------- right-looking panel step: factor 64x64 diag block at (s,s) + TRSM rows below ----------
__global__ __launch_bounds__(512) void k_panel(float* La, float* Lw1, float* __restrict__ ld, int s) {
  float* A = (blockIdx.x == 0) ? La : Lw1;
  const int j0 = s * 64;
  int tid = threadIdx.x;
  __shared__ float sm[64][65];
  __shared__ float smT[64][68];
  __shared__ float rinv[64];
  float logacc = 0.f;

  // load 64x64 diag block
  for (int i = tid; i < 4096; i += 512) {
    int r = i >> 6, c = i & 63;
    sm[r][c] = A[(size_t)(j0 + r) * K_N + j0 + c];
  }
  __syncthreads();

  // factor A11 (32x32)
  factor32(sm, 0, tid, logacc);
  __syncthreads();

  // TRSM A21 (rows 32..63 vs L11)
  if (tid < 32) {
    int r = 32 + tid;
    float x[32];
#pragma unroll
    for (int c = 0; c < 32; ++c) x[c] = sm[r][c];
#pragma unroll
    for (int c = 0; c < 32; ++c) {
      x[c] = x[c] / sm[c][c];
#pragma unroll
      for (int k = c + 1; k < 32; ++k)
        x[k] -= x[c] * sm[k][c];
    }
#pragma unroll
    for (int c = 0; c < 32; ++c) sm[r][c] = x[c];
  }
  __syncthreads();

  // A22 -= A21 @ A21^T  (full 32x32 for symmetry)
  for (int i = tid; i < 1024; i += 512) {
    int r = 32 + (i >> 5), c = 32 + (i & 31);
    float accv = 0.f;
#pragma unroll
    for (int k = 0; k < 32; ++k) accv += sm[r][k] * sm[c][k];
    sm[r][c] -= accv;
  }
  __syncthreads();

  // factor A22
  factor32(sm, 32, tid, logacc);
  __syncthreads();

  // build transposed L (smT[c][k] = L[k][c]) + diag reciprocals
  for (int i = tid; i < 4096; i += 512) {
    int r = i >> 6, c = i & 63;
    smT[c][r] = sm[r][c];
  }
  if (tid < 64) rinv[tid] = 1.0f / sm[tid][tid];
  __syncthreads();

  // big TRSM: rows j0+64 .. 511, one row per thread
  int rrow = j0 + 64 + tid;
  if (rrow < K_N) {
    float x[64];
#pragma unroll
    for (int q = 0; q < 16; ++q) {
      float4 f = *(const float4*)&A[(size_t)rrow * K_N + j0 + 4 * q];
      x[4 * q] = f.x; x[4 * q + 1] = f.y; x[4 * q + 2] = f.z; x[4 * q + 3] = f.w;
    }
#pragma unroll
    for (int c = 0; c < 64; ++c) {
      x[c] *= rinv[c];
#pragma unroll
      for (int k = c + 1; k < 64; ++k)
        x[k] -= x[c] * smT[c][k];
    }
#pragma unroll
    for (int q = 0; q < 16; ++q) {
      float4 f;
      f.x = x[4 * q]; f.y = x[4 * q + 1]; f.z = x[4 * q + 2]; f.w = x[4 * q + 3];
      *(float4*)&A[(size_t)rrow * K_N + j0 + 4 * q] = f;
    }
  }

  // write diag block back
  for (int i = tid; i < 4096; i += 512) {
    int r = i >> 6, c = i & 63;
    A[(size_t)(j0 + r) * K_N + j0 + c] = sm[r][c];
  }
  if (tid == 0) ld[blockIdx.x * 8 + s] = logacc;
}

// ---------- trailing update: C[bi,bj] -= Lp[bi] @ Lp[bj]^T  (rank-64) ----------
__global__ __launch_bounds__(256) void k_update(float* La, float* Lw1, int s) {
  float* A = (blockIdx.y == 0) ? La : Lw1;
  int nt = 7 - s;
  int p = blockIdx.x;
  int bj = 0;
  while (p >= nt - bj) { p -= nt - bj; ++bj; }
  int bi = bj + p;
  int r0g = (s + 1 + bi) * 64, c0g = (s + 1 + bj) * 64, k0g = s * 64;

  __shared__ float As[64][68];   // As[k][r] = L[r0g+r][k0g+k]
  __shared__ float Bs[64][68];   // Bs[k][c] = L[c0g+c][k0g+k]
  int tid = threadIdx.x;
  for (int i = tid; i < 1024; i += 256) {
    int r = i >> 4, kq = (i & 15) << 2;
    float4 f = *(const float4*)&A[(size_t)(r0g + r) * K_N + k0g + kq];
    As[kq + 0][r] = f.x; As[kq + 1][r] = f.y; As[kq + 2][r] = f.z; As[kq + 3][r] = f.w;
    float4 g = *(const float4*)&A[(size_t)(c0g + r) * K_N + k0g + kq];
    Bs[kq + 0][r] = g.x; Bs[kq + 1][r] = g.y; Bs[kq + 2][r] = g.z; Bs[kq + 3][r] = g.w;
  }
  __syncthreads();

  int r0 = (tid >> 4) * 4, c0 = (tid & 15) * 4;
  float acc[4][4];
#pragma unroll
  for (int i = 0; i < 4; ++i)
#pragma unroll
    for (int j = 0; j < 4; ++j) acc[i][j] = 0.f;
#pragma unroll 4
  for (int k = 0; k < 64; ++k) {
    float4 av = *(const float4*)&As[k][r0];
    float4 bv = *(const float4*)&Bs[k][c0];
    acc[0][0] += av.x * bv.x; acc[0][1] += av.x * bv.y; acc[0][2] += av.x * bv.z; acc[0][3] += av.x * bv.w;
    acc[1][0] += av.y * bv.x; acc[1][1] += av.y * bv.y; acc[1][2] += av.y * bv.z; acc[1][3] += av.y * bv.w;
    acc[2][0] += av.z * bv.x; acc[2][1] += av.z * bv.y; acc[2][2] += av.z * bv.z; acc[2][3] += av.z * bv.w;
    acc[3][0] += av.w * bv.x; acc[3][1] += av.w * bv.y; acc[3][2] += av.w * bv.z; acc[3][3] += av.w * bv.w;
  }
#pragma unroll
  for (int i = 0; i < 4; ++i) {
    float* cp = &A[(size_t)(r0g + r0 + i) * K_N + c0g + c0];
#pragma unroll
    for (int j = 0; j < 4; ++j) cp[j] = cp[j] - acc[i][j];
  }
}

// ---------- combine ----------
__global__ void k_combine(const float* __restrict__ ld, const float* __restrict__ tr, float* __restrict__ out) {
  float l0 = 0.f, l1 = 0.f;
#pragma unroll
  for (int s = 0; s < 8; ++s) { l0 += ld[s]; l1 += ld[8 + s]; }
  out[0] = -l0 - l1 - (float)K_N + tr[0];
}

extern "C" void kernel_launch(void* const* d_in, const int* in_sizes, int n_in,
                              void* d_out, int out_size, void* d_ws, size_t ws_size,
                              hipStream_t stream) {
  const float* X  = (const float*)d_in[0];   // inputs  [V,128]
  const float* T  = (const float*)d_in[1];   // targets [K,K]
  const int*   ei = (const int*)d_in[2];     // edge_index [2,E]
  const float* P  = (const float*)d_in[3];   // pmat [K,V]
  float* out = (float*)d_out;
  char* ws = (char*)d_ws;

  // workspace layout (bytes); [0, 1314816) is one contiguous zero-memset region
  int*      cnt  = (int*)(ws + 0);
  float*    tr   = (float*)(ws + 16);
  float*    ld   = (float*)(ws + 32);            // 16 floats
  unsigned* htab = (unsigned*)(ws + 4096);       // 65536 u32 (256 KB) -> 266240
  float*    La   = (float*)(ws + 266240);        // K*K (1 MB) -> 1314816  (zeroed; lower-tri filled)
  float*    Lw1  = (float*)(ws + 1314816);       // K*K (1 MB) -> 2363392  (copied from T in k_pre)
  int*      si   = (int*)(ws + 2363392);         // 16384 ints -> 2428928
  int*      sj   = (int*)(ws + 2428928);         // 16384 ints -> 2494464
  float*    sw   = (float*)(ws + 2494464);       // 16384 floats -> 2560000
  float*    PT   = (float*)(ws + 2560000);       // V*K floats (16 MB) -> 19337216

  hipMemsetAsync(ws, 0, 1314816, stream);        // cnt, tr, ld, htab, La

  k_pre<<<NB_TR + NB_ED + NB_CP, 256, 0, stream>>>(P, PT, X, ei, cnt, si, sj, sw, htab, T, Lw1);
  k_syrk<<<dim3(36, NZ_SYRK), 256, 0, stream>>>(cnt, si, sj, sw, PT, La, T, tr);

  for (int s = 0; s < 8; ++s) {
    k_panel<<<2, 512, 0, stream>>>(La, Lw1, ld, s);
    int nt = 7 - s;
    if (nt > 0) k_update<<<dim3(nt * (nt + 1) / 2, 2), 256, 0, stream>>>(La, Lw1, s);
  }
  k_combine<<<1, 1, 0, stream>>>(ld, tr, out);
}